// Round 10
// baseline (411.857 us; speedup 1.0000x reference)
//
#include <hip/hip_runtime.h>
#include <hip/hip_bf16.h>

typedef float f32x4 __attribute__((ext_vector_type(4)));
typedef short s16x8 __attribute__((ext_vector_type(8)));

__device__ __forceinline__ unsigned short f32_to_bf16(float f){
    union { float f; unsigned u; } v; v.f = f;
    unsigned r = v.u + 0x7fffu + ((v.u >> 16) & 1u);   // RNE
    return (unsigned short)(r >> 16);
}
__device__ __forceinline__ unsigned pack2(float a, float b){
    float2 t; t.x = a; t.y = b;
    __hip_bfloat162 h = __float22bfloat162_rn(t);      // v_cvt_pk_bf16_f32
    union { __hip_bfloat162 h; unsigned u; } c; c.h = h;
    return c.u;
}

template<int N> __device__ __forceinline__ void wait_vmcnt(){
    if constexpr (N == 0)       asm volatile("s_waitcnt vmcnt(0)"  ::: "memory");
    else if constexpr (N == 1)  asm volatile("s_waitcnt vmcnt(1)"  ::: "memory");
    else if constexpr (N == 2)  asm volatile("s_waitcnt vmcnt(2)"  ::: "memory");
    else if constexpr (N == 3)  asm volatile("s_waitcnt vmcnt(3)"  ::: "memory");
    else if constexpr (N == 4)  asm volatile("s_waitcnt vmcnt(4)"  ::: "memory");
    else if constexpr (N == 6)  asm volatile("s_waitcnt vmcnt(6)"  ::: "memory");
    else if constexpr (N == 8)  asm volatile("s_waitcnt vmcnt(8)"  ::: "memory");
    else if constexpr (N == 9)  asm volatile("s_waitcnt vmcnt(9)"  ::: "memory");
    else static_assert(N == 0, "add wait case");
    __builtin_amdgcn_sched_barrier(0);
}

// first/has2-resolved counted wait: N = ops issued after the DMA batch we need.
template<int A, int B, int C, int D>
__device__ __forceinline__ void wait_sel(bool first, bool has2){
    if (first) { if (has2) wait_vmcnt<A>(); else wait_vmcnt<B>(); }
    else       { if (has2) wait_vmcnt<C>(); else wait_vmcnt<D>(); }
}

// LDS-publish barrier: waits DS ops only; vmcnt (DMA/stores) stays in flight.
__device__ __forceinline__ void bar_sync(){
    asm volatile("s_waitcnt lgkmcnt(0)" ::: "memory");
    __builtin_amdgcn_s_barrier();
    __builtin_amdgcn_sched_barrier(0);
}

// async global->LDS DMA, 16B per lane; lds dest wave-uniform base + lane*16.
__device__ __forceinline__ void dma16(const float* g, float* l){
    __builtin_amdgcn_global_load_lds(
        (const __attribute__((address_space(1))) unsigned int*)g,
        (__attribute__((address_space(3))) unsigned int*)l, 16, 0, 0);
}

// ---------- l = 1,2 body: NT=4, depth-2 DMA pipeline, per-WG W-frag build ----
// ML=5: waves split (row-tile th, col-half ch) -> A-frag LDS reads halved.
// ML=3: 4-way col split (single row-tile).
template<int ML>
__device__ __forceinline__
void lx_body(const float* __restrict__ x, const float* __restrict__ W,
             float* __restrict__ out, int yoff, int wg, int G, int ntiles,
             char* smem)
{
    constexpr int BLK  = 128 * ML;          // dwords per node-block (640 / 384)
    constexpr int NTB  = 4 * BLK;           // dwords per tile (2560 / 1536)
    constexpr int CH   = NTB / 256;         // 256-dword chunks: 10 / 6
    constexpr int HI   = CH / 4 + 1;        // chunks for waves 0-1: 3 / 2
    constexpr int LO   = CH / 4;            // chunks for waves 2-3: 2 / 1
    constexpr int RROWS= 4 * ML;            // real rows: 20 / 12
    constexpr int RTC  = (RROWS + 15) / 16; // row-tiles: 2 / 1
    constexpr int LDSS = 136;               // bf16 elems per lbf row (272 B)
    constexpr int CG   = (RTC >= 2) ? 2 : 4;// col-groups of waves
    constexpr int NTF  = 8 / CG;            // 16-col frags per wave: 4 / 2

    float*          lin  = (float*)smem;                       // [2][NTB]
    unsigned short* lbf  = (unsigned short*)(smem + 2*NTB*4);  // RTC*16 rows
    float*          lout = (float*)(smem + 2*NTB*4 + RTC*16*LDSS*2);

    const int tid = threadIdx.x;
    const int wv  = tid >> 6, ln = tid & 63;
    const int l16 = ln & 15,  lhi = ln >> 4;
    const int th  = wv / CG;                // row-tile owner (0 for ML=3)
    const int ch  = wv % CG;                // col-group
    const int colbase = ch * (NTF * 16);

    // ---- B frags (W^T + I) built from fp32 W, once per persistent WG
    s16x8 bfr[4][NTF];
    #pragma unroll
    for (int s = 0; s < 4; ++s) {
        const int k0 = s * 32 + lhi * 8;
        #pragma unroll
        for (int tf = 0; tf < NTF; ++tf) {
            const int d = colbase + tf * 16 + l16;
            const float4 w0 = *reinterpret_cast<const float4*>(W + d * 128 + k0);
            const float4 w1 = *reinterpret_cast<const float4*>(W + d * 128 + k0 + 4);
            const float w8[8] = {w0.x,w0.y,w0.z,w0.w,w1.x,w1.y,w1.z,w1.w};
            union { s16x8 v; unsigned short us[8]; } b;
            #pragma unroll
            for (int j = 0; j < 8; ++j)
                b.us[j] = f32_to_bf16(w8[j] + ((d == k0 + j) ? 1.0f : 0.0f));
            bfr[s][tf] = b.v;
        }
    }

    auto dma_tile = [&](int t, int cur) {
        const float* gb = x + (size_t)t * 4 * 2304 + yoff;
        float* lb = lin + cur * NTB;
        #pragma unroll
        for (int c = wv; c < CH; c += 4) {
            const int dw = c * 256 + ln * 4;
            const int nl = dw / BLK, r = dw - nl * BLK;
            dma16(gb + (size_t)nl * 2304 + r, lb + c * 256);
        }
    };
    auto flush_tile = [&](int t) {
        float* gb = out + (size_t)t * 4 * 2304 + yoff;
        #pragma unroll
        for (int c = wv; c < CH; c += 4) {
            const int dw = c * 256 + ln * 4;
            const int nl = dw / BLK, r = dw - nl * BLK;
            *reinterpret_cast<float4*>(gb + (size_t)nl * 2304 + r) =
                *reinterpret_cast<const float4*>(&lout[dw]);
        }
    };

    int t = wg, cur = 0;
    bool has1 = (t + G) < ntiles;
    dma_tile(t, 0);
    if (has1) dma_tile(t + G, 1);
    if (wv < 2) { if (has1) wait_vmcnt<HI>(); else wait_vmcnt<0>(); }
    else        { if (has1) wait_vmcnt<LO>(); else wait_vmcnt<0>(); }
    bar_sync();

    bool first = true;
    while (true) {
        // ---- pack: lin[cur] -> lbf (bf16 de-interleaved rows); wave = node
        {
            const float* sp = lin + cur * NTB + wv * BLK + ln * 2 * ML;
            float v[2 * ML];
            #pragma unroll
            for (int i = 0; i < ML; ++i) {            // 2 channels x ML, b64 reads
                const float2 t2 = *reinterpret_cast<const float2*>(sp + i * 2);
                v[i * 2] = t2.x; v[i * 2 + 1] = t2.y;
            }
            #pragma unroll
            for (int mm = 0; mm < ML; ++mm)
                *reinterpret_cast<unsigned*>(&lbf[(wv * ML + mm) * LDSS + ln * 2]) =
                    pack2(v[mm], v[ML + mm]);
        }
        bar_sync();                       // lbf published; lin[cur] free

        const bool has2 = (t + 2 * G) < ntiles;
        if (has2) dma_tile(t + 2 * G, cur);   // depth-2 refill

        // ---- MFMA from lbf; wave owns (row-tile th) x (cols colbase..+NTF*16)
        f32x4 acc[NTF];
        #pragma unroll
        for (int tf = 0; tf < NTF; ++tf) acc[tf] = (f32x4){0.f,0.f,0.f,0.f};

        #pragma unroll
        for (int s = 0; s < 4; ++s) {
            const int k0 = s * 32 + lhi * 8;
            const s16x8 af = *reinterpret_cast<const s16x8*>(
                &lbf[(th * 16 + l16) * LDSS + k0]);
            #pragma unroll
            for (int tf = 0; tf < NTF; ++tf)
                acc[tf] = __builtin_amdgcn_mfma_f32_16x16x32_bf16(af, bfr[s][tf], acc[tf], 0, 0, 0);
        }

        // ---- scatter acc -> lout in output (interleaved) layout
        #pragma unroll
        for (int tf = 0; tf < NTF; ++tf) {
            const int col = colbase + tf * 16 + l16;
            #pragma unroll
            for (int j = 0; j < 4; ++j) {
                const int row = th * 16 + lhi * 4 + j;
                if (row < RROWS) {
                    const int nl = row / ML;
                    lout[nl * BLK + col * ML + (row - nl * ML)] = acc[tf][j];
                }
            }
        }
        bar_sync();                       // lout published; lbf reads drained

        flush_tile(t);                    // fire-and-forget global stores

        has1 = (t + G) < ntiles;
        if (!has1) break;
        // need DMA(t+G) retired. newer ops (in-order vmcnt):
        //   flush(t-G)[unless first] + dma(t+2G)[if has2] + flush(t)
        if (wv < 2) wait_sel<2*HI, HI, 3*HI, 2*HI>(first, has2);
        else        wait_sel<2*LO, LO, 3*LO, 2*LO>(first, has2);
        bar_sync();
        t += G; cur ^= 1; first = false;
    }
}

// ---------- l = 0 body: NT=16, XOR-swizzled DMA, operand-swapped, direct st --
__device__ __forceinline__
void l0_body(const float* __restrict__ x, const float* __restrict__ W0p,
             const float* __restrict__ W0m, float* __restrict__ out,
             int wg, int G, int ntiles, char* smem)
{
    float* lin = (float*)smem;            // [2][4096] = 32 KB

    const int tid = threadIdx.x;
    const int wv  = tid >> 6, ln = tid & 63;
    const int l16 = ln & 15,  lhi = ln >> 4;
    const int b     = wv >> 1;            // parity (0e / 0o)
    const int dbase = (wv & 1) * 64;
    const float* __restrict__ W = b ? W0m : W0p;

    // A frags (W^T + I) from fp32 W, once per persistent WG
    s16x8 afr[4][4];
    #pragma unroll
    for (int s = 0; s < 4; ++s) {
        const int k0 = s * 32 + lhi * 8;
        #pragma unroll
        for (int dt = 0; dt < 4; ++dt) {
            const int d = dbase + dt * 16 + l16;
            const float4 w0 = *reinterpret_cast<const float4*>(W + d * 128 + k0);
            const float4 w1 = *reinterpret_cast<const float4*>(W + d * 128 + k0 + 4);
            const float w8[8] = {w0.x,w0.y,w0.z,w0.w,w1.x,w1.y,w1.z,w1.w};
            union { s16x8 v; unsigned short us[8]; } a;
            #pragma unroll
            for (int j = 0; j < 8; ++j)
                a.us[j] = f32_to_bf16(w8[j] + ((d == k0 + j) ? 1.0f : 0.0f));
            afr[s][dt] = a.v;
        }
    }

    auto dma_tile = [&](int t, int cur) {
        const float* gb = x + (size_t)t * 16 * 2304;
        float* lb = lin + cur * 4096;
        #pragma unroll
        for (int c = wv; c < 16; c += 4) {            // 4 chunks/wave
            const int dw = c * 256 + ln * 4;
            const int node = dw >> 8, r = dw & 255;
            // inverse-swizzled source; read side applies the same XOR
            dma16(gb + (size_t)node * 2304 + (r ^ ((node & 7) << 2)), lb + c * 256);
        }
    };

    int t = wg, cur = 0;
    bool has1 = (t + G) < ntiles;
    dma_tile(t, 0);
    if (has1) { dma_tile(t + G, 1); wait_vmcnt<4>(); } else wait_vmcnt<0>();
    bar_sync();

    while (true) {
        const bool has2 = (t + 2 * G) < ntiles;

        f32x4 acc[4];
        #pragma unroll
        for (int dt = 0; dt < 4; ++dt) acc[dt] = (f32x4){0.f,0.f,0.f,0.f};

        const float* bp = lin + cur * 4096;
        const int nb = l16 * 256;
        const int sw = (l16 & 7) << 2;
        #pragma unroll
        for (int s = 0; s < 4; ++s) {
            const int c0 = b * 128 + s * 32 + lhi * 8;
            const float4 v0 = *reinterpret_cast<const float4*>(&bp[nb + ((c0    ) ^ sw)]);
            const float4 v1 = *reinterpret_cast<const float4*>(&bp[nb + ((c0 + 4) ^ sw)]);
            union { s16x8 v; unsigned u[4]; } bf;
            bf.u[0] = pack2(v0.x, v0.y); bf.u[1] = pack2(v0.z, v0.w);
            bf.u[2] = pack2(v1.x, v1.y); bf.u[3] = pack2(v1.z, v1.w);
            #pragma unroll
            for (int dt = 0; dt < 4; ++dt)
                acc[dt] = __builtin_amdgcn_mfma_f32_16x16x32_bf16(afr[s][dt], bf.v, acc[dt], 0, 0, 0);
        }
        bar_sync();   // all waves done reading lin[cur]

        // direct stores: lane l16 = node, reg quad = 4 consecutive d (full lines)
        float* dst = out + ((size_t)t * 16 + l16) * 2304 + b * 128 + dbase + lhi * 4;
        #pragma unroll
        for (int dt = 0; dt < 4; ++dt) {
            float4 vv; vv.x = acc[dt][0]; vv.y = acc[dt][1];
                       vv.z = acc[dt][2]; vv.w = acc[dt][3];
            *reinterpret_cast<float4*>(dst + dt * 16) = vv;
        }

        if (has2) dma_tile(t + 2 * G, cur);
        has1 = (t + G) < ntiles;
        if (!has1) break;
        // ops after DMA(t+G): stores(t)[4] + dma(t+2G)[4 if has2]
        if (has2) wait_vmcnt<8>(); else wait_vmcnt<4>();
        bar_sync();
        t += G; cur ^= 1;
    }
}

// ---------- fused persistent kernel: 1024 WGs = 4/CU, traffic-balanced -------
// [0,576): lx5 (288/parity) | [576,912): lx3 (168/parity) | [912,1024): l0
#define SMEM_MAX 39424   // lx5: 2*2560*4 + 32*136*2 + 2560*4
__global__ __launch_bounds__(256, 4)
void fused_kernel(const float* __restrict__ x,
                  const float* __restrict__ W0p, const float* __restrict__ W0m,
                  const float* __restrict__ W1p, const float* __restrict__ W1m,
                  const float* __restrict__ W2p, const float* __restrict__ W2m,
                  float* __restrict__ out, int n4, int n16)
{
    __shared__ __attribute__((aligned(16))) char smem[SMEM_MAX];
    const int b = blockIdx.x;
    if (b < 576) {
        const int p = (b >= 288);
        lx_body<5>(x, p ? W2m : W2p, out, p ? 1664 : 1024, b - p * 288, 288, n4, smem);
    } else if (b < 912) {
        const int bb = b - 576;
        const int p = (bb >= 168);
        lx_body<3>(x, p ? W1m : W1p, out, p ? 640 : 256, bb - p * 168, 168, n4, smem);
    } else {
        l0_body(x, W0p, W0m, out, b - 912, 112, n16, smem);
    }
}

extern "C" void kernel_launch(void* const* d_in, const int* in_sizes, int n_in,
                              void* d_out, int out_size, void* d_ws, size_t ws_size,
                              hipStream_t stream) {
    const float* x   = (const float*)d_in[0];
    const float* W0p = (const float*)d_in[1];
    const float* W0m = (const float*)d_in[2];
    const float* W1p = (const float*)d_in[3];
    const float* W1m = (const float*)d_in[4];
    const float* W2p = (const float*)d_in[5];
    const float* W2m = (const float*)d_in[6];
    float* out = (float*)d_out;

    const int N = in_sizes[0] / 2304;   // 100000

    fused_kernel<<<1024, 256, 0, stream>>>(x, W0p, W0m, W1p, W1m, W2p, W2m,
                                           out, N / 4, N / 16);
}

// Round 11
// 389.689 us; speedup vs baseline: 1.0569x; 1.0569x over previous
//
#include <hip/hip_runtime.h>
#include <hip/hip_bf16.h>

typedef float f32x4 __attribute__((ext_vector_type(4)));
typedef short s16x8 __attribute__((ext_vector_type(8)));

__device__ __forceinline__ unsigned short f32_to_bf16(float f){
    union { float f; unsigned u; } v; v.f = f;
    unsigned r = v.u + 0x7fffu + ((v.u >> 16) & 1u);   // RNE
    return (unsigned short)(r >> 16);
}
__device__ __forceinline__ unsigned pack2(float a, float b){
    float2 t; t.x = a; t.y = b;
    __hip_bfloat162 h = __float22bfloat162_rn(t);      // v_cvt_pk_bf16_f32
    union { __hip_bfloat162 h; unsigned u; } c; c.h = h;
    return c.u;
}

template<int N> __device__ __forceinline__ void wait_vmcnt(){
    if constexpr (N == 0)       asm volatile("s_waitcnt vmcnt(0)"  ::: "memory");
    else if constexpr (N == 3)  asm volatile("s_waitcnt vmcnt(3)"  ::: "memory");
    else if constexpr (N == 4)  asm volatile("s_waitcnt vmcnt(4)"  ::: "memory");
    else if constexpr (N == 5)  asm volatile("s_waitcnt vmcnt(5)"  ::: "memory");
    else if constexpr (N == 8)  asm volatile("s_waitcnt vmcnt(8)"  ::: "memory");
    else if constexpr (N == 9)  asm volatile("s_waitcnt vmcnt(9)"  ::: "memory");
    else if constexpr (N == 15) asm volatile("s_waitcnt vmcnt(15)" ::: "memory");
    else static_assert(N == 0, "add wait case");
    __builtin_amdgcn_sched_barrier(0);
}

// LDS-publish barrier: waits DS ops only; vmcnt (DMA/stores) stays in flight.
__device__ __forceinline__ void bar_sync(){
    asm volatile("s_waitcnt lgkmcnt(0)" ::: "memory");
    __builtin_amdgcn_s_barrier();
    __builtin_amdgcn_sched_barrier(0);
}

// async global->LDS DMA, 16B per lane; lds dest wave-uniform base + lane*16.
__device__ __forceinline__ void dma16(const float* g, float* l){
    __builtin_amdgcn_global_load_lds(
        (const __attribute__((address_space(1))) unsigned int*)g,
        (__attribute__((address_space(3))) unsigned int*)l, 16, 0, 0);
}

// ---------- W pre-convert: wbf[w][d][c] = bf16(W[d][c] + (d==c)) -------------
__global__ __launch_bounds__(256)
void wconv_kernel(const float* __restrict__ W0p, const float* __restrict__ W0m,
                  const float* __restrict__ W1p, const float* __restrict__ W1m,
                  const float* __restrict__ W2p, const float* __restrict__ W2m,
                  unsigned short* __restrict__ wbf)
{
    const int idx = blockIdx.x * 256 + threadIdx.x;   // 384*256 = 98304
    const int w  = idx >> 14;
    const int rc = idx & 16383;
    const float* Wp;
    switch (w) {
        case 0: Wp = W0p; break;  case 1: Wp = W0m; break;
        case 2: Wp = W1p; break;  case 3: Wp = W1m; break;
        case 4: Wp = W2p; break;  default: Wp = W2m; break;
    }
    const float v = Wp[rc] + (((rc >> 7) == (rc & 127)) ? 1.0f : 0.0f);
    wbf[idx] = f32_to_bf16(v);
}

// ---------- l = 1,2: depth-2 DMA pipeline + wide-op pack ---------------------
template<int ML, int NT, int OCC>
__global__ __launch_bounds__(256, OCC)
void lx_dma(const float* __restrict__ x, const unsigned short* __restrict__ wbf,
            float* __restrict__ out, int yoff0, int yoff1, int w0, int ntiles)
{
    constexpr int BLK   = 128 * ML;          // dwords per node-block (640 / 384)
    constexpr int NTB   = NT * BLK;          // dwords per tile (5120 / 3072)
    constexpr int DI    = NTB * 4 / 4096;    // DMA instrs/thread: 5 / 3
    constexpr int SI    = DI;                // flush instrs/thread
    constexpr int RROWS = NT * ML;           // 40 / 24
    constexpr int RTC   = (RROWS + 15) / 16; // 3 / 2
    constexpr int PR    = RTC * 16;          // padded rows: 48 / 32
    constexpr int LDSS  = 136;               // bf16 elems per lbf row (272 B)
    constexpr int CPT   = NTB / 256;         // pack dwords/thread: 20 / 12
    constexpr int V4    = CPT / 4;           // pack b128 reads: 5 / 3

    __shared__ __attribute__((aligned(16))) float          lin[2][NTB];
    __shared__ __attribute__((aligned(16))) unsigned short lbf[PR * LDSS];
    __shared__ __attribute__((aligned(16))) float          lout[NTB];

    const int parity = blockIdx.y;
    const int yoff   = parity ? yoff1 : yoff0;
    const unsigned short* wb = wbf + (size_t)(w0 + parity) * 16384;

    const int tid = threadIdx.x;
    const int wv  = tid >> 6, ln = tid & 63;
    const int l16 = ln & 15,  lhi = ln >> 4;

    // B frags (W^T+I): once per persistent WG; 4-way col split -> 32 VGPR
    s16x8 bfr[4][2];
    #pragma unroll
    for (int s = 0; s < 4; ++s)
        #pragma unroll
        for (int tf = 0; tf < 2; ++tf)
            bfr[s][tf] = *reinterpret_cast<const s16x8*>(
                wb + (wv * 32 + tf * 16 + l16) * 128 + s * 32 + lhi * 8);

    // pack mapping: 32 threads per node; thread owns 4 channels x all m
    const int pnl = tid >> 5;            // node 0..NT-1 (NT==8)
    const int pc0 = (tid & 31) * 4;      // first channel

    auto dma_tile = [&](int t, int cur) {
        const float* gb = x + (size_t)t * NT * 2304 + yoff;
        #pragma unroll
        for (int j = 0; j < DI; ++j) {
            const int chunk = j * 4 + wv;
            const int dw = chunk * 256 + ln * 4;   // lane's dword idx in tile
            const int nl = dw / BLK;
            const int r  = dw - nl * BLK;
            dma16(gb + (size_t)nl * 2304 + r, &lin[cur][chunk * 256]);
        }
    };
    auto flush_tile = [&](int t) {
        float* gb = out + (size_t)t * NT * 2304 + yoff;
        #pragma unroll
        for (int i = 0; i < SI; ++i) {
            const int dw = (i * 256 + tid) * 4;
            const int nl = dw / BLK;
            const int r  = dw - nl * BLK;
            *reinterpret_cast<float4*>(gb + (size_t)nl * 2304 + r) =
                *reinterpret_cast<const float4*>(&lout[dw]);
        }
    };

    const int G = (int)gridDim.x;
    int t = blockIdx.x, cur = 0;
    dma_tile(t, 0);
    if (t + G < ntiles) { dma_tile(t + G, 1); wait_vmcnt<DI>(); }
    else                { wait_vmcnt<0>(); }
    bar_sync();

    while (true) {
        // ---- pack: lin[cur] (fp32 native) -> lbf (bf16 de-interleaved rows)
        {
            float v[CPT];
            const float* sp = &lin[cur][pnl * BLK + pc0 * ML];
            #pragma unroll
            for (int i = 0; i < V4; ++i) {
                const float4 t4 = *reinterpret_cast<const float4*>(sp + i * 4);
                v[i*4+0] = t4.x; v[i*4+1] = t4.y; v[i*4+2] = t4.z; v[i*4+3] = t4.w;
            }
            #pragma unroll
            for (int mm = 0; mm < ML; ++mm) {
                unsigned* wp = reinterpret_cast<unsigned*>(&lbf[(pnl * ML + mm) * LDSS + pc0]);
                wp[0] = pack2(v[mm],          v[ML + mm]);
                wp[1] = pack2(v[2*ML + mm],   v[3*ML + mm]);
            }
        }
        bar_sync();                      // lbf published; lin[cur] free

        if (t + 2 * G < ntiles) dma_tile(t + 2 * G, cur);   // depth-2 refill

        // ---- MFMA from lbf (b128 frags)
        f32x4 acc[RTC][2];
        #pragma unroll
        for (int rt = 0; rt < RTC; ++rt) {
            acc[rt][0] = (f32x4){0.f,0.f,0.f,0.f};
            acc[rt][1] = (f32x4){0.f,0.f,0.f,0.f};
        }
        #pragma unroll
        for (int s = 0; s < 4; ++s) {
            const int k0 = s * 32 + lhi * 8;
            #pragma unroll
            for (int rt = 0; rt < RTC; ++rt) {
                const s16x8 af = *reinterpret_cast<const s16x8*>(
                    &lbf[(rt * 16 + l16) * LDSS + k0]);
                acc[rt][0] = __builtin_amdgcn_mfma_f32_16x16x32_bf16(af, bfr[s][0], acc[rt][0], 0, 0, 0);
                acc[rt][1] = __builtin_amdgcn_mfma_f32_16x16x32_bf16(af, bfr[s][1], acc[rt][1], 0, 0, 0);
            }
        }

        // ---- scatter acc -> lout in output (interleaved) layout
        #pragma unroll
        for (int rt = 0; rt < RTC; ++rt)
            #pragma unroll
            for (int tf = 0; tf < 2; ++tf) {
                const int col = wv * 32 + tf * 16 + l16;
                #pragma unroll
                for (int j = 0; j < 4; ++j) {
                    const int row = rt * 16 + lhi * 4 + j;
                    if (row < RROWS) {
                        const int nl = row / ML;
                        lout[nl * BLK + col * ML + (row - nl * ML)] = acc[rt][tf][j];
                    }
                }
            }
        bar_sync();                      // lout published; lbf reads drained

        flush_tile(t);                   // fire-and-forget global stores

        if (t + G >= ntiles) break;
        // newest in flight: flush(t)[SI] + dma(t+2G)[DI] + flush(t-G)[SI];
        // DMA(t+G) is older -> retired after this wait (in-order vmcnt).
        wait_vmcnt<2 * SI + DI>();
        bar_sync();
        t += G; cur ^= 1;
    }
}

// ---------- l = 0: DMA-staged (XOR-swizzled), operand-swapped, direct stores -
template<int WGS>
__global__ __launch_bounds__(256, 4)
void l0_dma(const float* __restrict__ x, const unsigned short* __restrict__ wbf,
            float* __restrict__ out, int ntiles)
{
    constexpr int NT = 16;
    constexpr int DI = 4;   // 16 KB / (256 thr * 16 B)
    constexpr int SI = 4;   // direct stores per thread

    __shared__ __attribute__((aligned(16))) float lin[2][NT * 256];

    const int tid = threadIdx.x;
    const int wv  = tid >> 6, ln = tid & 63;
    const int l16 = ln & 15,  lhi = ln >> 4;
    const int b     = wv >> 1;            // parity (0e / 0o)
    const int dbase = (wv & 1) * 64;
    const unsigned short* wb = wbf + b * 16384;

    // A frags (W^T+I): once per persistent WG
    s16x8 afr[4][4];
    #pragma unroll
    for (int s = 0; s < 4; ++s)
        #pragma unroll
        for (int dt = 0; dt < 4; ++dt)
            afr[s][dt] = *reinterpret_cast<const s16x8*>(
                wb + (dbase + dt * 16 + l16) * 128 + s * 32 + lhi * 8);

    auto dma_tile = [&](int t, int cur) {
        const float* gb = x + (size_t)t * NT * 2304;
        float* lb = &lin[cur][0];
        #pragma unroll
        for (int j = 0; j < DI; ++j) {
            const int chunk = j * 4 + wv;
            const int dw   = chunk * 256 + ln * 4;
            const int node = dw >> 8;
            const int r    = dw & 255;
            // inverse-swizzled source; read side applies the same XOR
            dma16(gb + (size_t)node * 2304 + (r ^ ((node & 7) << 2)), lb + chunk * 256);
        }
    };

    const int tstart = blockIdx.x;
    int cur = 0;
    dma_tile(tstart, 0);
    if (tstart + WGS < ntiles) { dma_tile(tstart + WGS, 1); wait_vmcnt<4>(); }
    else                       { wait_vmcnt<0>(); }
    bar_sync();

    for (int t = tstart; t < ntiles; t += WGS, cur ^= 1) {
        const bool has1 = (t + WGS)     < ntiles;
        const bool has2 = (t + 2 * WGS) < ntiles;

        // fragments: swizzled b128 reads + cvt_pk; MFMA (A=W rows, B=x nodes)
        f32x4 acc[4];
        #pragma unroll
        for (int dt = 0; dt < 4; ++dt) acc[dt] = (f32x4){0.f,0.f,0.f,0.f};

        const float* bp = &lin[cur][0];
        const int nb = l16 * 256;
        const int sw = (l16 & 7) << 2;
        #pragma unroll
        for (int s = 0; s < 4; ++s) {
            const int c0 = b * 128 + s * 32 + lhi * 8;
            const float4 v0 = *reinterpret_cast<const float4*>(&bp[nb + ((c0    ) ^ sw)]);
            const float4 v1 = *reinterpret_cast<const float4*>(&bp[nb + ((c0 + 4) ^ sw)]);
            union { s16x8 v; unsigned u[4]; } bf;
            bf.u[0] = pack2(v0.x, v0.y); bf.u[1] = pack2(v0.z, v0.w);
            bf.u[2] = pack2(v1.x, v1.y); bf.u[3] = pack2(v1.z, v1.w);
            #pragma unroll
            for (int dt = 0; dt < 4; ++dt)
                acc[dt] = __builtin_amdgcn_mfma_f32_16x16x32_bf16(afr[s][dt], bf.v, acc[dt], 0, 0, 0);
        }

        bar_sync();   // all waves done reading buf[cur]

        // direct stores: lane l16 = node, reg quad = 4 consecutive d (full lines)
        float* dst = out + ((size_t)t * NT + l16) * 2304 + b * 128 + dbase + lhi * 4;
        #pragma unroll
        for (int dt = 0; dt < 4; ++dt) {
            float4 vv; vv.x = acc[dt][0]; vv.y = acc[dt][1];
                       vv.z = acc[dt][2]; vv.w = acc[dt][3];
            *reinterpret_cast<float4*>(dst + dt * 16) = vv;
        }

        if (has2) dma_tile(t + 2 * WGS, cur);
        if (has1) { if (has2) wait_vmcnt<8>(); else wait_vmcnt<4>(); }
        bar_sync();
    }
}

extern "C" void kernel_launch(void* const* d_in, const int* in_sizes, int n_in,
                              void* d_out, int out_size, void* d_ws, size_t ws_size,
                              hipStream_t stream) {
    const float* x   = (const float*)d_in[0];
    const float* W0p = (const float*)d_in[1];
    const float* W0m = (const float*)d_in[2];
    const float* W1p = (const float*)d_in[3];
    const float* W1m = (const float*)d_in[4];
    const float* W2p = (const float*)d_in[5];
    const float* W2m = (const float*)d_in[6];
    float* out = (float*)d_out;
    unsigned short* wbf = (unsigned short*)d_ws;   // 6*128*128 bf16 = 196.6 KB

    const int N = in_sizes[0] / 2304;   // 100000

    wconv_kernel<<<384, 256, 0, stream>>>(W0p, W0m, W1p, W1m, W2p, W2m, wbf);

    // offsets (dwords): 0e:0, 0o:128 | 1e:256, 1o:640 | 2e:1024, 2o:1664
    // lx5: 73 KB LDS -> 2 WG/CU; lx3: 44.5 KB -> 3 WG/CU; depth-2 pipeline.
    lx_dma<5, 8, 2><<<dim3(256, 2), 256, 0, stream>>>(x, wbf, out, 1024, 1664, 4, N / 8);
    lx_dma<3, 8, 3><<<dim3(384, 2), 256, 0, stream>>>(x, wbf, out, 256,  640,  2, N / 8);
    l0_dma<1024>   <<<1024,         256, 0, stream>>>(x, wbf, out, N / 16);
}